// Round 4
// baseline (240.112 us; speedup 1.0000x reference)
//
#include <hip/hip_runtime.h>

#define N 8192

typedef __attribute__((ext_vector_type(8))) short short8;
typedef __attribute__((ext_vector_type(4))) float f32x4;

__device__ __forceinline__ unsigned short f2bf(float f) {
    union { float f; unsigned int u; } v; v.f = f;
    unsigned int r = v.u + 0x7FFFu + ((v.u >> 16) & 1u);  // round-to-nearest-even
    return (unsigned short)(r >> 16);
}

// ---------------------------------------------------------------------------
// Barrier-free aggregation: y_part[ks] = adj[rows, kslice] @ h
// Each WAVE owns 16*RT rows x klen k, fully independent: A fragments loaded
// straight from global to VGPRs, B fragments from the small L2-resident hT.
// k-map per MFMA pair (superstep of 64): lane (hi,j): mfma0 k=16hi+j (j=0..7),
// mfma1 k=16hi+8+j. Same bijection for A and B => correct dot product.
// MODE 0: adj f32 (no writeback)  MODE 1: adj f32 + bf16 writeback  MODE 2: bf16.
// ---------------------------------------------------------------------------
template<int RT, int NCT, int MODE>
struct Frag {
    f32x4 af[MODE == 2 ? 1 : RT][4];
    short8 ab[MODE == 2 ? RT : 1][2];
    short8 b[NCT][2];
};

template<int NC, int RT, int MODE>
__global__ __launch_bounds__(256) void agg_kernel(
    const float* __restrict__ adjf,
    const unsigned short* __restrict__ adjb,
    unsigned short* __restrict__ adjbo,
    const unsigned short* __restrict__ hT,   // [NC][N] bf16 row-major
    float* __restrict__ y,                   // [S][N][NC] f32 partials
    int klen)
{
    constexpr int NCT = NC / 16;
    constexpr int RB = N / (16 * RT);        // row-blocks
    using FR = Frag<RT, NCT, MODE>;

    const int tid = threadIdx.x;
    const int w = tid >> 6, l = tid & 63;
    const int hi = l >> 4, lr = l & 15;
    const int gw = blockIdx.x * 4 + w;
    const int rb = gw % RB;
    const int ks = gw / RB;
    const int row0 = rb * 16 * RT;
    const int k0 = ks * klen;
    const int nss = klen >> 6;

    f32x4 acc[RT][NCT];
    #pragma unroll
    for (int i = 0; i < RT; ++i)
        #pragma unroll
        for (int j = 0; j < NCT; ++j) acc[i][j] = f32x4{0.f, 0.f, 0.f, 0.f};

    auto load = [&](FR& f, int ss) {
        const size_t kb = (size_t)(k0 + ss * 64 + 16 * hi);
        #pragma unroll
        for (int rt = 0; rt < RT; ++rt) {
            const size_t base = (size_t)(row0 + 16 * rt + lr) * N + kb;
            if constexpr (MODE == 2) {
                const short8* p = reinterpret_cast<const short8*>(adjb + base);
                f.ab[rt][0] = p[0]; f.ab[rt][1] = p[1];
            } else {
                const f32x4* p = reinterpret_cast<const f32x4*>(adjf + base);
                f.af[rt][0] = __builtin_nontemporal_load(p + 0);
                f.af[rt][1] = __builtin_nontemporal_load(p + 1);
                f.af[rt][2] = __builtin_nontemporal_load(p + 2);
                f.af[rt][3] = __builtin_nontemporal_load(p + 3);
            }
        }
        #pragma unroll
        for (int ct = 0; ct < NCT; ++ct) {
            const short8* p = reinterpret_cast<const short8*>(
                hT + (size_t)(16 * ct + lr) * N + kb);
            f.b[ct][0] = p[0]; f.b[ct][1] = p[1];
        }
    };

    auto compute = [&](FR& f, int ss) {
        const size_t kb = (size_t)(k0 + ss * 64 + 16 * hi);
        #pragma unroll
        for (int rt = 0; rt < RT; ++rt) {
            short8 s0, s1;
            if constexpr (MODE == 2) {
                s0 = f.ab[rt][0]; s1 = f.ab[rt][1];
            } else {
                f32x4 v0 = f.af[rt][0], v1 = f.af[rt][1];
                f32x4 v2 = f.af[rt][2], v3 = f.af[rt][3];
                s0[0] = (short)f2bf(v0[0]); s0[1] = (short)f2bf(v0[1]);
                s0[2] = (short)f2bf(v0[2]); s0[3] = (short)f2bf(v0[3]);
                s0[4] = (short)f2bf(v1[0]); s0[5] = (short)f2bf(v1[1]);
                s0[6] = (short)f2bf(v1[2]); s0[7] = (short)f2bf(v1[3]);
                s1[0] = (short)f2bf(v2[0]); s1[1] = (short)f2bf(v2[1]);
                s1[2] = (short)f2bf(v2[2]); s1[3] = (short)f2bf(v2[3]);
                s1[4] = (short)f2bf(v3[0]); s1[5] = (short)f2bf(v3[1]);
                s1[6] = (short)f2bf(v3[2]); s1[7] = (short)f2bf(v3[3]);
                if constexpr (MODE == 1) {
                    const size_t base = (size_t)(row0 + 16 * rt + lr) * N + kb;
                    *reinterpret_cast<short8*>(adjbo + base) = s0;
                    *reinterpret_cast<short8*>(adjbo + base + 8) = s1;
                }
            }
            #pragma unroll
            for (int ct = 0; ct < NCT; ++ct) {
                acc[rt][ct] = __builtin_amdgcn_mfma_f32_16x16x32_bf16(
                    s0, f.b[ct][0], acc[rt][ct], 0, 0, 0);
                acc[rt][ct] = __builtin_amdgcn_mfma_f32_16x16x32_bf16(
                    s1, f.b[ct][1], acc[rt][ct], 0, 0, 0);
            }
        }
    };

    FR f0, f1;
    load(f0, 0);
    for (int ss = 0; ss < nss; ss += 2) {
        if (ss + 1 < nss) load(f1, ss + 1);
        compute(f0, ss);
        if (ss + 2 < nss) load(f0, ss + 2);
        if (ss + 1 < nss) compute(f1, ss + 1);
    }

    // D layout: col = lane&15, row = 4*(lane>>4)+reg  (verified R1)
    float* yp = y + (size_t)ks * N * NC;
    #pragma unroll
    for (int rt = 0; rt < RT; ++rt)
        #pragma unroll
        for (int ct = 0; ct < NCT; ++ct)
            #pragma unroll
            for (int r = 0; r < 4; ++r)
                yp[(size_t)(row0 + 16 * rt + 4 * hi + r) * NC + 16 * ct + lr] =
                    acc[rt][ct][r];
}

// ---------------------------------------------------------------------------
// lin0: hT = bf16((x @ W0 + b0)^T)   plain row-major [16][N]
// ---------------------------------------------------------------------------
__global__ __launch_bounds__(256) void lin0_kernel(
    const float* __restrict__ x, const float* __restrict__ W,
    const float* __restrict__ b, unsigned short* __restrict__ hT)
{
    __shared__ float xs[64][129];
    const int tid = threadIdx.x;
    const int row0 = blockIdx.x * 64;
    #pragma unroll
    for (int it = 0; it < 8; ++it) {
        int idx = tid + it * 256;
        int r = idx >> 5, q = idx & 31;
        float4 v = *reinterpret_cast<const float4*>(x + (size_t)(row0 + r) * 128 + 4 * q);
        xs[r][4 * q + 0] = v.x; xs[r][4 * q + 1] = v.y;
        xs[r][4 * q + 2] = v.z; xs[r][4 * q + 3] = v.w;
    }
    __syncthreads();
    const int w = tid >> 6, l = tid & 63;
    float acc[4] = {b[w], b[w + 4], b[w + 8], b[w + 12]};
    for (int k = 0; k < 128; ++k) {
        float xv = xs[l][k];
        #pragma unroll
        for (int cc = 0; cc < 4; ++cc) acc[cc] += xv * W[k * 16 + w + 4 * cc];
    }
    #pragma unroll
    for (int cc = 0; cc < 4; ++cc) {
        int c = w + 4 * cc;
        hT[(size_t)c * N + row0 + l] = f2bf(acc[cc]);
    }
}

// ---------------------------------------------------------------------------
// mid linear: hT = bf16((relu(sum_s y_s) @ W + b)^T)   plain row-major
// ---------------------------------------------------------------------------
template<int NIN, int NOUT, int S>
__global__ __launch_bounds__(256) void mid_linear_kernel(
    const float* __restrict__ y,     // [S][N][NIN]
    const float* __restrict__ W,     // [NIN][NOUT]
    const float* __restrict__ b,
    unsigned short* __restrict__ hT) // [NOUT][N]
{
    __shared__ float xs[64][NIN + 1];
    const int tid = threadIdx.x;
    const int row0 = blockIdx.x * 64;
    constexpr int NF4 = 64 * NIN / 4;
    #pragma unroll
    for (int idx0 = 0; idx0 < NF4; idx0 += 256) {
        int idx = idx0 + tid;
        if (NF4 >= 256 || idx < NF4) {
            int r = idx / (NIN / 4), q = idx % (NIN / 4);
            size_t off = (size_t)(row0 + r) * NIN + 4 * q;
            float4 v = *reinterpret_cast<const float4*>(y + off);
            #pragma unroll
            for (int s = 1; s < S; ++s) {
                float4 t = *reinterpret_cast<const float4*>(y + (size_t)s * N * NIN + off);
                v.x += t.x; v.y += t.y; v.z += t.z; v.w += t.w;
            }
            xs[r][4 * q + 0] = fmaxf(v.x, 0.f);
            xs[r][4 * q + 1] = fmaxf(v.y, 0.f);
            xs[r][4 * q + 2] = fmaxf(v.z, 0.f);
            xs[r][4 * q + 3] = fmaxf(v.w, 0.f);
        }
    }
    __syncthreads();
    const int w = tid >> 6, l = tid & 63;
    constexpr int CC = NOUT / 4;
    float acc[CC];
    #pragma unroll
    for (int cc = 0; cc < CC; ++cc) acc[cc] = b[w + 4 * cc];
    for (int k = 0; k < NIN; ++k) {
        float xv = xs[l][k];
        #pragma unroll
        for (int cc = 0; cc < CC; ++cc) acc[cc] += xv * W[k * NOUT + w + 4 * cc];
    }
    #pragma unroll
    for (int cc = 0; cc < CC; ++cc) {
        int c = w + 4 * cc;
        hT[(size_t)c * N + row0 + l] = f2bf(acc[cc]);
    }
}

// ---------------------------------------------------------------------------
// head: out = relu(relu(sum_s y_s) @ Wo0 + bo0) @ Wo1 + bo1, 16 rows/block
// ---------------------------------------------------------------------------
template<int S>
__global__ __launch_bounds__(256) void head_kernel(
    const float* __restrict__ y,   // [S][N][64]
    const float* __restrict__ Wo0, const float* __restrict__ bo0,
    const float* __restrict__ Wo1, const float* __restrict__ bo1,
    float* __restrict__ out)
{
    __shared__ float xr[16][68];
    __shared__ float hid[16][36];
    const int tid = threadIdx.x;
    const int row0 = blockIdx.x * 16;
    {
        int r = tid >> 4, q = tid & 15;
        float4 v = *reinterpret_cast<const float4*>(
            y + ((size_t)(row0 + r)) * 64 + 4 * q);
        #pragma unroll
        for (int s = 1; s < S; ++s) {
            float4 t = *reinterpret_cast<const float4*>(
                y + ((size_t)s * N + row0 + r) * 64 + 4 * q);
            v.x += t.x; v.y += t.y; v.z += t.z; v.w += t.w;
        }
        xr[r][4 * q + 0] = fmaxf(v.x, 0.f);
        xr[r][4 * q + 1] = fmaxf(v.y, 0.f);
        xr[r][4 * q + 2] = fmaxf(v.z, 0.f);
        xr[r][4 * q + 3] = fmaxf(v.w, 0.f);
    }
    __syncthreads();
    {
        int j = tid & 31, r0 = tid >> 5;
        #pragma unroll
        for (int rr = r0; rr < 16; rr += 8) {
            float a = bo0[j];
            #pragma unroll
            for (int k = 0; k < 64; ++k) a += xr[rr][k] * Wo0[k * 32 + j];
            hid[rr][j] = fmaxf(a, 0.f);
        }
    }
    __syncthreads();
    if (tid < 160) {
        int r = tid / 10, c = tid % 10;
        float a = bo1[c];
        #pragma unroll
        for (int k = 0; k < 32; ++k) a += hid[r][k] * Wo1[k * 10 + c];
        out[(size_t)(row0 + r) * 10 + c] = a;
    }
}

extern "C" void kernel_launch(void* const* d_in, const int* in_sizes, int n_in,
                              void* d_out, int out_size, void* d_ws, size_t ws_size,
                              hipStream_t stream) {
    const float* x   = (const float*)d_in[0];
    const float* adj = (const float*)d_in[1];
    const float* W0  = (const float*)d_in[2];
    const float* b0  = (const float*)d_in[3];
    const float* W1  = (const float*)d_in[4];
    const float* b1  = (const float*)d_in[5];
    const float* W2  = (const float*)d_in[6];
    const float* b2  = (const float*)d_in[7];
    const float* Wo0 = (const float*)d_in[8];
    const float* bo0 = (const float*)d_in[9];
    const float* Wo1 = (const float*)d_in[10];
    const float* bo1 = (const float*)d_in[11];
    float* out = (float*)d_out;

    char* ws = (char*)d_ws;
    constexpr int S = 16;                    // k-splits (klen = 512)
    constexpr int KLEN = N / S;
    float* y_part          = (float*)ws;                          // <= 32 MiB
    unsigned short* hT     = (unsigned short*)(ws + (32u << 20)); // 1 MiB
    unsigned short* adj_b  = (unsigned short*)(ws + (34u << 20)); // 128 MiB
    const size_t NEED_FULL = ((size_t)34 << 20) + (size_t)N * N * 2;
    const bool cache = ws_size >= NEED_FULL;

    // waves = (N/32 rowblocks) * S = 4096 -> 1024 blocks of 4 waves
    constexpr int AGG_BLOCKS = (N / 32) * S / 4;

    lin0_kernel<<<128, 256, 0, stream>>>(x, W0, b0, hT);

    if (cache)
        agg_kernel<16, 2, 1><<<AGG_BLOCKS, 256, 0, stream>>>(adj, nullptr, adj_b, hT, y_part, KLEN);
    else
        agg_kernel<16, 2, 0><<<AGG_BLOCKS, 256, 0, stream>>>(adj, nullptr, nullptr, hT, y_part, KLEN);

    mid_linear_kernel<16, 32, S><<<128, 256, 0, stream>>>(y_part, W1, b1, hT);

    if (cache)
        agg_kernel<32, 2, 2><<<AGG_BLOCKS, 256, 0, stream>>>(nullptr, adj_b, nullptr, hT, y_part, KLEN);
    else
        agg_kernel<32, 2, 0><<<AGG_BLOCKS, 256, 0, stream>>>(adj, nullptr, nullptr, hT, y_part, KLEN);

    mid_linear_kernel<32, 64, S><<<128, 256, 0, stream>>>(y_part, W2, b2, hT);

    if (cache)
        agg_kernel<64, 2, 2><<<AGG_BLOCKS, 256, 0, stream>>>(nullptr, adj_b, nullptr, hT, y_part, KLEN);
    else
        agg_kernel<64, 2, 0><<<AGG_BLOCKS, 256, 0, stream>>>(adj, nullptr, nullptr, hT, y_part, KLEN);

    head_kernel<S><<<512, 256, 0, stream>>>(y_part, Wo0, bo0, Wo1, bo1, out);
}

// Round 5
// 169.504 us; speedup vs baseline: 1.4166x; 1.4166x over previous
//
#include <hip/hip_runtime.h>

#define N 8192

typedef __attribute__((ext_vector_type(8))) short short8;
typedef __attribute__((ext_vector_type(4))) float f32x4;

__device__ __forceinline__ unsigned short f2bf(float f) {
    union { float f; unsigned int u; } v; v.f = f;
    unsigned int r = v.u + 0x7FFFu + ((v.u >> 16) & 1u);  // round-to-nearest-even
    return (unsigned short)(r >> 16);
}

__device__ __forceinline__ void gl2lds16(const void* g, void* l) {
    __builtin_amdgcn_global_load_lds(
        (const __attribute__((address_space(1))) unsigned int*)g,
        (__attribute__((address_space(3))) unsigned int*)l, 16, 0, 0);
}

#define BAR_SCHED() do { __builtin_amdgcn_s_barrier(); \
                         __builtin_amdgcn_sched_barrier(0); } while (0)

// ---------------------------------------------------------------------------
// Aggregation: y_part[ks] = adj[rows, kslice] @ h
// MODE 0: adj f32 (no writeback)  MODE 1: f32 + pre-swizzled bf16 writeback
//   (BK=128, register prefetch, raw barriers: vmcnt(0) only at barrier #1,
//    stores + next-tile prefetch stay in flight across barrier #2)
// MODE 2: linear gl2lds of pre-swizzled bf16, DOUBLE-BUFFERED LDS with
//   counted s_waitcnt vmcnt(KW) — current tile's loads issued 1 iter ago.
// hT stored PRE-SWIZZLED (idx ^ ((c&7)<<3)); LDS fragment reads use
// byte ^ ((row&7)<<4). BM=64 rows, 4 waves, wave w -> rows [16w,16w+16).
// ---------------------------------------------------------------------------
template<int NC, int BK, int MODE>
__global__ __launch_bounds__(256) void agg_kernel(
    const float* __restrict__ adj,
    const unsigned short* __restrict__ adj_b_in,
    unsigned short* __restrict__ adj_b_out,
    const unsigned short* __restrict__ hT,   // [NC][N] bf16, pre-swizzled
    float* __restrict__ y,                   // [S][N][NC] f32 partials
    int klen)
{
    constexpr int BM = 64;
    constexpr int NCT = NC / 16;
    constexpr int ROWB = BK * 2;             // bytes per LDS row

    const int tid = threadIdx.x;
    const int w  = tid >> 6;
    const int l  = tid & 63;
    const int hi = l >> 4;
    const int lr = l & 15;
    const int row0 = blockIdx.x * BM;
    const int k00  = blockIdx.y * klen;
    const int nt   = klen / BK;

    f32x4 acc[NCT];
    #pragma unroll
    for (int i = 0; i < NCT; ++i) acc[i] = f32x4{0.f, 0.f, 0.f, 0.f};

    if constexpr (MODE == 2) {
        __shared__ unsigned short as2_[2][BM * BK];
        __shared__ unsigned short hs2_[2][NC * BK];
        constexpr int TA = (BM * ROWB) / 1024;   // 1KB chunks, adj tile
        constexpr int TH = (NC * ROWB) / 1024;   // 1KB chunks, hT tile
        constexpr int GR = ROWB / 16;            // 16B granules per row
        constexpr int RPC = 1024 / ROWB;         // rows per chunk
        constexpr int KW = (TA + TH) / 4;        // per-wave gl2lds per stage

        auto stage = [&](char* ab, char* hb, int t) {
            const int kb = k00 + t * BK;
            #pragma unroll
            for (int i = w; i < TA; i += 4) {
                int r = i * RPC + l / GR, g = l % GR;
                gl2lds16(adj_b_in + (size_t)(row0 + r) * N + kb + 8 * g,
                         ab + i * 1024);
            }
            #pragma unroll
            for (int i = w; i < TH; i += 4) {
                int c = i * RPC + l / GR, g = l % GR;
                gl2lds16(hT + (size_t)c * N + kb + 8 * g, hb + i * 1024);
            }
        };

        stage((char*)as2_[0], (char*)hs2_[0], 0);
        for (int t = 0; t < nt; ++t) {
            char* ca = (char*)as2_[t & 1];
            char* ch = (char*)hs2_[t & 1];
            char* na = (char*)as2_[(t & 1) ^ 1];
            char* nh = (char*)hs2_[(t & 1) ^ 1];
            if (t + 1 < nt) {
                stage(na, nh, t + 1);
                asm volatile("s_waitcnt vmcnt(%0)" :: "n"(KW) : "memory");
            } else {
                asm volatile("s_waitcnt vmcnt(0)" ::: "memory");
            }
            BAR_SCHED();
            #pragma unroll
            for (int kk = 0; kk < BK; kk += 32) {
                const int arow = 16 * w + lr;
                short8 a = *reinterpret_cast<const short8*>(
                    ca + arow * ROWB + ((2 * kk + 16 * hi) ^ ((arow & 7) << 4)));
                #pragma unroll
                for (int ct = 0; ct < NCT; ++ct) {
                    const int bcol = 16 * ct + lr;
                    short8 b = *reinterpret_cast<const short8*>(
                        ch + bcol * ROWB + ((2 * kk + 16 * hi) ^ ((bcol & 7) << 4)));
                    acc[ct] = __builtin_amdgcn_mfma_f32_16x16x32_bf16(a, b, acc[ct], 0, 0, 0);
                }
            }
            asm volatile("s_waitcnt lgkmcnt(0)" ::: "memory");
            BAR_SCHED();
        }
    } else {
        // MODE 0/1: BK==128. 8 float4/thread reg prefetch, single LDS buffer.
        __shared__ unsigned short as_[BM * BK];
        __shared__ unsigned short hs_[NC * BK];
        char* asb = (char*)as_;
        char* hsb = (char*)hs_;
        constexpr int LV = 8;
        constexpr int TH = (NC * ROWB) / 1024;
        float4 pf[LV];
        ushort4 u[LV];
        #pragma unroll
        for (int it = 0; it < LV; ++it) {
            int idx = tid + it * 256, r = idx >> 5, q = idx & 31;
            const f32x4* p = reinterpret_cast<const f32x4*>(
                adj + (size_t)(row0 + r) * N + k00 + 4 * q);
            f32x4 t0 = __builtin_nontemporal_load(p);
            pf[it] = float4{t0[0], t0[1], t0[2], t0[3]};
        }
        for (int t = 0; t < nt; ++t) {
            const int kb = k00 + t * BK;
            // hT tile: linear gllds (content pre-swizzled)
            #pragma unroll
            for (int i = w; i < TH; i += 4) {
                int c = i * 4 + l / 16;   // 4 rows per 1KB chunk (ROWB=256)
                int g = l % 16;
                gl2lds16(hT + (size_t)c * N + kb + 8 * g, hsb + i * 1024);
            }
            // convert + swizzled LDS write
            #pragma unroll
            for (int it = 0; it < LV; ++it) {
                int idx = tid + it * 256, r = idx >> 5, q = idx & 31;
                u[it].x = f2bf(pf[it].x); u[it].y = f2bf(pf[it].y);
                u[it].z = f2bf(pf[it].z); u[it].w = f2bf(pf[it].w);
                *reinterpret_cast<ushort4*>(
                    asb + r * ROWB + ((8 * q) ^ ((r & 7) << 4))) = u[it];
            }
            asm volatile("s_waitcnt vmcnt(0) lgkmcnt(0)" ::: "memory");
            BAR_SCHED();
            // writeback + next-tile prefetch: in flight across barrier #2
            if (MODE == 1) {
                #pragma unroll
                for (int it = 0; it < LV; ++it) {
                    int idx = tid + it * 256, r = idx >> 5, q = idx & 31;
                    *reinterpret_cast<ushort4*>(
                        adj_b_out + (size_t)(row0 + r) * N + kb +
                        ((4 * q) ^ ((r & 7) << 3))) = u[it];
                }
            }
            if (t + 1 < nt) {
                #pragma unroll
                for (int it = 0; it < LV; ++it) {
                    int idx = tid + it * 256, r = idx >> 5, q = idx & 31;
                    const f32x4* p = reinterpret_cast<const f32x4*>(
                        adj + (size_t)(row0 + r) * N + kb + BK + 4 * q);
                    f32x4 t0 = __builtin_nontemporal_load(p);
                    pf[it] = float4{t0[0], t0[1], t0[2], t0[3]};
                }
            }
            #pragma unroll
            for (int kk = 0; kk < BK; kk += 32) {
                const int arow = 16 * w + lr;
                short8 a = *reinterpret_cast<const short8*>(
                    asb + arow * ROWB + ((2 * kk + 16 * hi) ^ ((arow & 7) << 4)));
                #pragma unroll
                for (int ct = 0; ct < NCT; ++ct) {
                    const int bcol = 16 * ct + lr;
                    short8 b = *reinterpret_cast<const short8*>(
                        hsb + bcol * ROWB + ((2 * kk + 16 * hi) ^ ((bcol & 7) << 4)));
                    acc[ct] = __builtin_amdgcn_mfma_f32_16x16x32_bf16(a, b, acc[ct], 0, 0, 0);
                }
            }
            asm volatile("s_waitcnt lgkmcnt(0)" ::: "memory");
            BAR_SCHED();
        }
    }
    // write partials: D layout col=lane&15, row=4*(lane>>4)+reg (verified R1)
    float* yp = y + (size_t)blockIdx.y * N * NC;
    #pragma unroll
    for (int ct = 0; ct < NCT; ++ct) {
        #pragma unroll
        for (int r = 0; r < 4; ++r) {
            yp[(size_t)(row0 + 16 * w + 4 * hi + r) * NC + 16 * ct + lr] = acc[ct][r];
        }
    }
}

// ---------------------------------------------------------------------------
// lin0: hT = bf16((x @ W0 + b0)^T), pre-swizzled columns
// ---------------------------------------------------------------------------
__global__ __launch_bounds__(256) void lin0_kernel(
    const float* __restrict__ x, const float* __restrict__ W,
    const float* __restrict__ b, unsigned short* __restrict__ hT)
{
    __shared__ float xs[64][129];
    const int tid = threadIdx.x;
    const int row0 = blockIdx.x * 64;
    #pragma unroll
    for (int it = 0; it < 8; ++it) {
        int idx = tid + it * 256;
        int r = idx >> 5, q = idx & 31;
        float4 v = *reinterpret_cast<const float4*>(x + (size_t)(row0 + r) * 128 + 4 * q);
        xs[r][4 * q + 0] = v.x; xs[r][4 * q + 1] = v.y;
        xs[r][4 * q + 2] = v.z; xs[r][4 * q + 3] = v.w;
    }
    __syncthreads();
    const int w = tid >> 6, l = tid & 63;
    float acc[4] = {b[w], b[w + 4], b[w + 8], b[w + 12]};
    for (int k = 0; k < 128; ++k) {
        float xv = xs[l][k];
        #pragma unroll
        for (int cc = 0; cc < 4; ++cc) acc[cc] += xv * W[k * 16 + w + 4 * cc];
    }
    #pragma unroll
    for (int cc = 0; cc < 4; ++cc) {
        int c = w + 4 * cc;
        hT[(size_t)c * N + ((row0 + l) ^ ((c & 7) << 3))] = f2bf(acc[cc]);
    }
}

// ---------------------------------------------------------------------------
// mid linear: hT = bf16((relu(sum_s y_s) @ W + b)^T), pre-swizzled columns
// ---------------------------------------------------------------------------
template<int NIN, int NOUT, int S>
__global__ __launch_bounds__(256) void mid_linear_kernel(
    const float* __restrict__ y,     // [S][N][NIN]
    const float* __restrict__ W,     // [NIN][NOUT]
    const float* __restrict__ b,
    unsigned short* __restrict__ hT) // [NOUT][N]
{
    __shared__ float xs[64][NIN + 1];
    const int tid = threadIdx.x;
    const int row0 = blockIdx.x * 64;
    constexpr int NF4 = 64 * NIN / 4;
    #pragma unroll
    for (int idx0 = 0; idx0 < NF4; idx0 += 256) {
        int idx = idx0 + tid;
        if (NF4 >= 256 || idx < NF4) {
            int r = idx / (NIN / 4), q = idx % (NIN / 4);
            size_t off = (size_t)(row0 + r) * NIN + 4 * q;
            float4 v = *reinterpret_cast<const float4*>(y + off);
            #pragma unroll
            for (int s = 1; s < S; ++s) {
                float4 t = *reinterpret_cast<const float4*>(y + (size_t)s * N * NIN + off);
                v.x += t.x; v.y += t.y; v.z += t.z; v.w += t.w;
            }
            xs[r][4 * q + 0] = fmaxf(v.x, 0.f);
            xs[r][4 * q + 1] = fmaxf(v.y, 0.f);
            xs[r][4 * q + 2] = fmaxf(v.z, 0.f);
            xs[r][4 * q + 3] = fmaxf(v.w, 0.f);
        }
    }
    __syncthreads();
    const int w = tid >> 6, l = tid & 63;
    constexpr int CC = NOUT / 4;
    float acc[CC];
    #pragma unroll
    for (int cc = 0; cc < CC; ++cc) acc[cc] = b[w + 4 * cc];
    for (int k = 0; k < NIN; ++k) {
        float xv = xs[l][k];
        #pragma unroll
        for (int cc = 0; cc < CC; ++cc) acc[cc] += xv * W[k * NOUT + w + 4 * cc];
    }
    #pragma unroll
    for (int cc = 0; cc < CC; ++cc) {
        int c = w + 4 * cc;
        hT[(size_t)c * N + ((row0 + l) ^ ((c & 7) << 3))] = f2bf(acc[cc]);
    }
}

// ---------------------------------------------------------------------------
// head: out = relu(relu(sum_s y_s) @ Wo0 + bo0) @ Wo1 + bo1, 16 rows/block
// ---------------------------------------------------------------------------
template<int S>
__global__ __launch_bounds__(256) void head_kernel(
    const float* __restrict__ y,   // [S][N][64]
    const float* __restrict__ Wo0, const float* __restrict__ bo0,
    const float* __restrict__ Wo1, const float* __restrict__ bo1,
    float* __restrict__ out)
{
    __shared__ float xr[16][68];
    __shared__ float hid[16][36];
    const int tid = threadIdx.x;
    const int row0 = blockIdx.x * 16;
    {
        int r = tid >> 4, q = tid & 15;
        float4 v = *reinterpret_cast<const float4*>(
            y + ((size_t)(row0 + r)) * 64 + 4 * q);
        #pragma unroll
        for (int s = 1; s < S; ++s) {
            float4 t = *reinterpret_cast<const float4*>(
                y + ((size_t)s * N + row0 + r) * 64 + 4 * q);
            v.x += t.x; v.y += t.y; v.z += t.z; v.w += t.w;
        }
        xr[r][4 * q + 0] = fmaxf(v.x, 0.f);
        xr[r][4 * q + 1] = fmaxf(v.y, 0.f);
        xr[r][4 * q + 2] = fmaxf(v.z, 0.f);
        xr[r][4 * q + 3] = fmaxf(v.w, 0.f);
    }
    __syncthreads();
    {
        int j = tid & 31, r0 = tid >> 5;
        #pragma unroll
        for (int rr = r0; rr < 16; rr += 8) {
            float a = bo0[j];
            #pragma unroll
            for (int k = 0; k < 64; ++k) a += xr[rr][k] * Wo0[k * 32 + j];
            hid[rr][j] = fmaxf(a, 0.f);
        }
    }
    __syncthreads();
    if (tid < 160) {
        int r = tid / 10, c = tid % 10;
        float a = bo1[c];
        #pragma unroll
        for (int k = 0; k < 32; ++k) a += hid[r][k] * Wo1[k * 10 + c];
        out[(size_t)(row0 + r) * 10 + c] = a;
    }
}

extern "C" void kernel_launch(void* const* d_in, const int* in_sizes, int n_in,
                              void* d_out, int out_size, void* d_ws, size_t ws_size,
                              hipStream_t stream) {
    const float* x   = (const float*)d_in[0];
    const float* adj = (const float*)d_in[1];
    const float* W0  = (const float*)d_in[2];
    const float* b0  = (const float*)d_in[3];
    const float* W1  = (const float*)d_in[4];
    const float* b1  = (const float*)d_in[5];
    const float* W2  = (const float*)d_in[6];
    const float* b2  = (const float*)d_in[7];
    const float* Wo0 = (const float*)d_in[8];
    const float* bo0 = (const float*)d_in[9];
    const float* Wo1 = (const float*)d_in[10];
    const float* bo1 = (const float*)d_in[11];
    float* out = (float*)d_out;

    char* ws = (char*)d_ws;
    constexpr int S = 16;                    // k-splits (klen = 512)
    constexpr int KLEN = N / S;
    float* y_part          = (float*)ws;                          // <= 32 MiB
    unsigned short* hT     = (unsigned short*)(ws + (32u << 20)); // 1 MiB
    unsigned short* adj_b  = (unsigned short*)(ws + (34u << 20)); // 128 MiB
    const size_t NEED_FULL = ((size_t)34 << 20) + (size_t)N * N * 2;
    const bool cache = ws_size >= NEED_FULL;

    lin0_kernel<<<128, 256, 0, stream>>>(x, W0, b0, hT);

    if (cache)
        agg_kernel<16, 128, 1><<<dim3(128, S), 256, 0, stream>>>(adj, nullptr, adj_b, hT, y_part, KLEN);
    else
        agg_kernel<16, 128, 0><<<dim3(128, S), 256, 0, stream>>>(adj, nullptr, nullptr, hT, y_part, KLEN);

    mid_linear_kernel<16, 32, S><<<128, 256, 0, stream>>>(y_part, W1, b1, hT);

    if (cache)
        agg_kernel<32, 64, 2><<<dim3(128, S), 256, 0, stream>>>(nullptr, adj_b, nullptr, hT, y_part, KLEN);
    else
        agg_kernel<32, 128, 0><<<dim3(128, S), 256, 0, stream>>>(adj, nullptr, nullptr, hT, y_part, KLEN);

    mid_linear_kernel<32, 64, S><<<128, 256, 0, stream>>>(y_part, W2, b2, hT);

    if (cache)
        agg_kernel<64, 64, 2><<<dim3(128, S), 256, 0, stream>>>(nullptr, adj_b, nullptr, hT, y_part, KLEN);
    else
        agg_kernel<64, 128, 0><<<dim3(128, S), 256, 0, stream>>>(adj, nullptr, nullptr, hT, y_part, KLEN);

    head_kernel<S><<<512, 256, 0, stream>>>(y_part, Wo0, bo0, Wo1, bo1, out);
}